// Round 1
// baseline (769.285 us; speedup 1.0000x reference)
//
#include <hip/hip_runtime.h>

// Problem constants (from reference)
#define N_NODES 100000
#define IN_C    128
#define OUT_C   200
#define SCAN_CHUNK 1024

// ---------------------------------------------------------------------------
// 1. degree count: deg[v] = in-degree (self-loop handled as +1 later)
// ---------------------------------------------------------------------------
__global__ void count_deg_kernel(const int* __restrict__ col, int E, int* __restrict__ deg) {
    int e = blockIdx.x * blockDim.x + threadIdx.x;
    if (e < E) atomicAdd(&deg[col[e]], 1);
}

__global__ void dinv_kernel(const int* __restrict__ deg, float* __restrict__ dinv, int n) {
    int v = blockIdx.x * blockDim.x + threadIdx.x;
    if (v < n) dinv[v] = rsqrtf((float)(deg[v] + 1));  // +1 self-loop; always >0
}

// ---------------------------------------------------------------------------
// 2. exclusive scan of deg -> CSR offsets (two-level, 98 blocks of 1024)
// ---------------------------------------------------------------------------
__global__ void scan1_kernel(const int* __restrict__ deg, int n, int* __restrict__ blockSums) {
    __shared__ int s[256];
    int base = blockIdx.x * SCAN_CHUNK;
    int sum = 0;
    for (int i = threadIdx.x; i < SCAN_CHUNK; i += 256) {
        int idx = base + i;
        sum += (idx < n) ? deg[idx] : 0;
    }
    s[threadIdx.x] = sum; __syncthreads();
    for (int off = 128; off > 0; off >>= 1) {
        if (threadIdx.x < off) s[threadIdx.x] += s[threadIdx.x + off];
        __syncthreads();
    }
    if (threadIdx.x == 0) blockSums[blockIdx.x] = s[0];
}

__global__ void scan2_kernel(int* __restrict__ blockSums, int nb) {
    if (threadIdx.x == 0 && blockIdx.x == 0) {
        int acc = 0;
        for (int i = 0; i < nb; i++) { int t = blockSums[i]; blockSums[i] = acc; acc += t; }
    }
}

__global__ void scan3_kernel(const int* __restrict__ deg, int n,
                             const int* __restrict__ blockSums,
                             int* __restrict__ offsets, int* __restrict__ cursor) {
    __shared__ int s[256];
    int base = blockIdx.x * SCAN_CHUNK;
    int vals[4];
    int tsum = 0;
    for (int j = 0; j < 4; j++) {
        int idx = base + threadIdx.x * 4 + j;
        vals[j] = (idx < n) ? deg[idx] : 0;
        tsum += vals[j];
    }
    s[threadIdx.x] = tsum; __syncthreads();
    // Hillis-Steele inclusive scan over 256 thread sums
    for (int off = 1; off < 256; off <<= 1) {
        int t = (threadIdx.x >= (unsigned)off) ? s[threadIdx.x - off] : 0;
        __syncthreads();
        s[threadIdx.x] += t;
        __syncthreads();
    }
    int excl = s[threadIdx.x] - tsum + blockSums[blockIdx.x];
    for (int j = 0; j < 4; j++) {
        int idx = base + threadIdx.x * 4 + j;
        if (idx < n) { offsets[idx] = excl; cursor[idx] = excl; }
        excl += vals[j];
    }
}

// ---------------------------------------------------------------------------
// 3. CSR fill: csr_src grouped by destination node
// ---------------------------------------------------------------------------
__global__ void fill_kernel(const int* __restrict__ rowi, const int* __restrict__ coli, int E,
                            int* __restrict__ cursor, int* __restrict__ csr_src) {
    int e = blockIdx.x * blockDim.x + threadIdx.x;
    if (e < E) {
        int c = coli[e];
        int p = atomicAdd(&cursor[c], 1);
        csr_src[p] = rowi[e];
    }
}

// ---------------------------------------------------------------------------
// 4. gather: agg[v] = dinv[v]^2 * x[v] + sum_{u->v} dinv[u]*dinv[v]*x[u]
//    one block (128 threads) per node; thread = channel
// ---------------------------------------------------------------------------
__global__ __launch_bounds__(128) void gather_kernel(
        const float* __restrict__ x, const float* __restrict__ dinv,
        const int* __restrict__ offsets, const int* __restrict__ deg,
        const int* __restrict__ csr_src, float* __restrict__ agg) {
    int v = blockIdx.x;
    int t = threadIdx.x;
    float dv = dinv[v];
    float acc = dv * dv * x[(size_t)v * IN_C + t];   // self-loop
    int start = offsets[v];
    int cnt = deg[v];
    for (int i = 0; i < cnt; i++) {
        int u = csr_src[start + i];                   // wave-uniform broadcast
        float nrm = dinv[u] * dv;
        acc += nrm * x[(size_t)u * IN_C + t];         // 512B coalesced row read
    }
    agg[(size_t)v * IN_C + t] = acc;
}

// ---------------------------------------------------------------------------
// 5. GEMM: out[M,200] = agg[M,128] @ W[128,200] + bias
//    BM=64 BN=64 BK=32, 256 threads, 4x4 register tile per thread
// ---------------------------------------------------------------------------
#define BM 64
#define BN 64
#define BK 32
__global__ __launch_bounds__(256) void gemm_kernel(
        const float* __restrict__ A, const float* __restrict__ W,
        const float* __restrict__ bias, float* __restrict__ out, int M) {
    __shared__ float As[BK][BM + 4];   // +4 pad keeps 16B alignment + breaks bank stride
    __shared__ float Bs[BK][BN];
    int tid = threadIdx.x;
    int row0 = blockIdx.x * BM;
    int col0 = blockIdx.y * BN;
    int tx = tid & 15, ty = tid >> 4;
    float acc[4][4] = {};

    for (int k0 = 0; k0 < IN_C; k0 += BK) {
        // A tile (transposed into LDS): 64 rows x 32 k
        {
            int kk = (tid & 7) * 4;
            int mm = tid >> 3;                 // 0..31
            for (int p = 0; p < 2; p++) {
                int m = mm + p * 32;
                int gr = row0 + m;
                float4 a;
                if (gr < M) a = *(const float4*)&A[(size_t)gr * IN_C + k0 + kk];
                else        a = make_float4(0.f, 0.f, 0.f, 0.f);
                As[kk + 0][m] = a.x; As[kk + 1][m] = a.y;
                As[kk + 2][m] = a.z; As[kk + 3][m] = a.w;
            }
        }
        // B tile: 32 k x 64 n  (OUT_C=200 is a multiple of 4 -> float4 chunks
        // are all-valid or all-invalid)
        {
            int nn = (tid & 15) * 4;
            int kk = tid >> 4;                 // 0..15
            for (int p = 0; p < 2; p++) {
                int k = kk + p * 16;
                int gc = col0 + nn;
                float4 b;
                if (gc < OUT_C) b = *(const float4*)&W[(size_t)(k0 + k) * OUT_C + gc];
                else            b = make_float4(0.f, 0.f, 0.f, 0.f);
                *(float4*)&Bs[k][nn] = b;
            }
        }
        __syncthreads();
        for (int k = 0; k < BK; k++) {
            float4 a = *(const float4*)&As[k][ty * 4];   // broadcast within 16-lane groups
            float4 b = *(const float4*)&Bs[k][tx * 4];
            float av[4] = {a.x, a.y, a.z, a.w};
            float bv[4] = {b.x, b.y, b.z, b.w};
            #pragma unroll
            for (int i = 0; i < 4; i++)
                #pragma unroll
                for (int j = 0; j < 4; j++)
                    acc[i][j] += av[i] * bv[j];
        }
        __syncthreads();
    }

    int gc = col0 + tx * 4;
    if (gc < OUT_C) {
        float4 bb = *(const float4*)&bias[gc];
        for (int i = 0; i < 4; i++) {
            int gr = row0 + ty * 4 + i;
            if (gr < M) {
                float4 o;
                o.x = acc[i][0] + bb.x; o.y = acc[i][1] + bb.y;
                o.z = acc[i][2] + bb.z; o.w = acc[i][3] + bb.w;
                *(float4*)&out[(size_t)gr * OUT_C + gc] = o;
            }
        }
    }
}

// ---------------------------------------------------------------------------
extern "C" void kernel_launch(void* const* d_in, const int* in_sizes, int n_in,
                              void* d_out, int out_size, void* d_ws, size_t ws_size,
                              hipStream_t stream) {
    const float* x  = (const float*)d_in[0];
    const int*   ei = (const int*)d_in[1];
    const float* W1 = (const float*)d_in[2];
    const float* b1 = (const float*)d_in[3];
    const float* W2 = (const float*)d_in[4];
    const float* b2 = (const float*)d_in[5];

    const int n = in_sizes[0] / IN_C;      // 100000
    const int E = in_sizes[1] / 2;         // 1600000
    const int* row = ei;                   // src
    const int* col = ei + E;               // dst

    float* mu = (float*)d_out;
    float* ls = (float*)d_out + (size_t)n * OUT_C;

    // workspace layout (byte offsets, all 16B aligned)
    char* ws = (char*)d_ws;
    int*   deg      = (int*)  (ws + 0);                         // n ints
    float* dinv     = (float*)(ws + 524288);                    // n floats
    int*   offsets  = (int*)  (ws + 1048576);                   // n ints
    int*   cursor   = (int*)  (ws + 1572864);                   // n ints
    int*   bsums    = (int*)  (ws + 2097152);                   // scan partials
    int*   csr_src  = (int*)  (ws + 2162688);                   // E ints
    float* agg      = (float*)(ws + 2162688 + 6400000);         // n*128 floats
    // total ~59.8 MB

    const int nb_scan = (n + SCAN_CHUNK - 1) / SCAN_CHUNK;      // 98

    hipMemsetAsync(deg, 0, (size_t)n * sizeof(int), stream);

    count_deg_kernel<<<(E + 255) / 256, 256, 0, stream>>>(col, E, deg);
    dinv_kernel<<<(n + 255) / 256, 256, 0, stream>>>(deg, dinv, n);

    scan1_kernel<<<nb_scan, 256, 0, stream>>>(deg, n, bsums);
    scan2_kernel<<<1, 64, 0, stream>>>(bsums, nb_scan);
    scan3_kernel<<<nb_scan, 256, 0, stream>>>(deg, n, bsums, offsets, cursor);

    fill_kernel<<<(E + 255) / 256, 256, 0, stream>>>(row, col, E, cursor, csr_src);

    gather_kernel<<<n, 128, 0, stream>>>(x, dinv, offsets, deg, csr_src, agg);

    dim3 ggrid((n + BM - 1) / BM, (OUT_C + BN - 1) / BN);
    gemm_kernel<<<ggrid, 256, 0, stream>>>(agg, W1, b1, mu, n);
    gemm_kernel<<<ggrid, 256, 0, stream>>>(agg, W2, b2, ls, n);
}

// Round 2
// 665.565 us; speedup vs baseline: 1.1558x; 1.1558x over previous
//
#include <hip/hip_runtime.h>

#define N_NODES 100000
#define IN_C    128
#define OUT_C   200
#define SCAN_CHUNK 1024
#define NT_TILES 13            // ceil(200/16)
#define KT_TILES 4             // 128/32

typedef __bf16 bf16_t;
typedef bf16_t bf16x8 __attribute__((ext_vector_type(8)));
typedef float  f32x4  __attribute__((ext_vector_type(4)));

// ---- bf16 bit helpers (RNE) -----------------------------------------------
__device__ __forceinline__ unsigned int bf16_bits(float f) {
    unsigned int u = __builtin_bit_cast(unsigned int, f);
    return (u + 0x7FFFu + ((u >> 16) & 1u)) >> 16;
}
__device__ __forceinline__ float bf16_lo(unsigned int p) {
    return __builtin_bit_cast(float, p << 16);
}
__device__ __forceinline__ float bf16_hi(unsigned int p) {
    return __builtin_bit_cast(float, p & 0xFFFF0000u);
}

// ---------------------------------------------------------------------------
// 1. degree count
// ---------------------------------------------------------------------------
__global__ void count_deg_kernel(const int* __restrict__ col, int E, int* __restrict__ deg) {
    int e = blockIdx.x * blockDim.x + threadIdx.x;
    if (e < E) atomicAdd(&deg[col[e]], 1);
}

__global__ void dinv_kernel(const int* __restrict__ deg, float* __restrict__ dinv, int n) {
    int v = blockIdx.x * blockDim.x + threadIdx.x;
    if (v < n) dinv[v] = rsqrtf((float)(deg[v] + 1));  // +1 self-loop
}

// ---------------------------------------------------------------------------
// 2. xs = dinv[v] * x[v]  ->  packed bf16x2 (one uint per 2 channels)
// ---------------------------------------------------------------------------
__global__ void convert_xs_kernel(const float* __restrict__ x, const float* __restrict__ dinv,
                                  unsigned int* __restrict__ xs2, int n) {
    int id = blockIdx.x * blockDim.x + threadIdx.x;   // n*64 total
    if (id >= n * 64) return;
    int v = id >> 6;
    float dv = dinv[v];
    float2 f = ((const float2*)x)[id];
    unsigned int lo = bf16_bits(f.x * dv);
    unsigned int hi = bf16_bits(f.y * dv);
    xs2[id] = lo | (hi << 16);
}

// ---------------------------------------------------------------------------
// 3. exclusive scan of deg -> CSR offsets
// ---------------------------------------------------------------------------
__global__ void scan1_kernel(const int* __restrict__ deg, int n, int* __restrict__ blockSums) {
    __shared__ int s[256];
    int base = blockIdx.x * SCAN_CHUNK;
    int sum = 0;
    for (int i = threadIdx.x; i < SCAN_CHUNK; i += 256) {
        int idx = base + i;
        sum += (idx < n) ? deg[idx] : 0;
    }
    s[threadIdx.x] = sum; __syncthreads();
    for (int off = 128; off > 0; off >>= 1) {
        if (threadIdx.x < off) s[threadIdx.x] += s[threadIdx.x + off];
        __syncthreads();
    }
    if (threadIdx.x == 0) blockSums[blockIdx.x] = s[0];
}

__global__ void scan2_kernel(int* __restrict__ blockSums, int nb) {
    if (threadIdx.x == 0 && blockIdx.x == 0) {
        int acc = 0;
        for (int i = 0; i < nb; i++) { int t = blockSums[i]; blockSums[i] = acc; acc += t; }
    }
}

__global__ void scan3_kernel(const int* __restrict__ deg, int n,
                             const int* __restrict__ blockSums,
                             int* __restrict__ offsets, int* __restrict__ cursor) {
    __shared__ int s[256];
    int base = blockIdx.x * SCAN_CHUNK;
    int vals[4];
    int tsum = 0;
    for (int j = 0; j < 4; j++) {
        int idx = base + threadIdx.x * 4 + j;
        vals[j] = (idx < n) ? deg[idx] : 0;
        tsum += vals[j];
    }
    s[threadIdx.x] = tsum; __syncthreads();
    for (int off = 1; off < 256; off <<= 1) {
        int t = (threadIdx.x >= (unsigned)off) ? s[threadIdx.x - off] : 0;
        __syncthreads();
        s[threadIdx.x] += t;
        __syncthreads();
    }
    int excl = s[threadIdx.x] - tsum + blockSums[blockIdx.x];
    for (int j = 0; j < 4; j++) {
        int idx = base + threadIdx.x * 4 + j;
        if (idx < n) { offsets[idx] = excl; cursor[idx] = excl; }
        excl += vals[j];
    }
}

// ---------------------------------------------------------------------------
// 4. CSR fill
// ---------------------------------------------------------------------------
__global__ void fill_kernel(const int* __restrict__ rowi, const int* __restrict__ coli, int E,
                            int* __restrict__ cursor, int* __restrict__ csr_src) {
    int e = blockIdx.x * blockDim.x + threadIdx.x;
    if (e < E) {
        int c = coli[e];
        int p = atomicAdd(&cursor[c], 1);
        csr_src[p] = rowi[e];
    }
}

// ---------------------------------------------------------------------------
// 5. gather: agg[v] = dv * ( xs[v] + sum_{u->v} xs[u] )   (bf16 in, bf16 out)
//    one wave per node, lane = channel-pair; 4 nodes per 256-block
// ---------------------------------------------------------------------------
__global__ __launch_bounds__(256) void gather_kernel(
        const unsigned int* __restrict__ xs2, const float* __restrict__ dinv,
        const int* __restrict__ offsets, const int* __restrict__ deg,
        const int* __restrict__ csr_src, unsigned int* __restrict__ agg2, int n) {
    int wave = threadIdx.x >> 6;
    int lane = threadIdx.x & 63;
    int v = blockIdx.x * 4 + wave;
    if (v >= n) return;
    float dv = dinv[v];
    int start = offsets[v];
    int cnt = deg[v];
    unsigned int s = xs2[(size_t)v * 64 + lane];       // self term (already dinv[v]-scaled)
    float ax = bf16_lo(s), ay = bf16_hi(s);
    for (int i = 0; i < cnt; i++) {
        int u = csr_src[start + i];                    // wave-uniform broadcast
        unsigned int t = xs2[(size_t)u * 64 + lane];   // 256B coalesced per wave
        ax += bf16_lo(t);
        ay += bf16_hi(t);
    }
    ax *= dv; ay *= dv;
    agg2[(size_t)v * 64 + lane] = bf16_bits(ax) | (bf16_bits(ay) << 16);
}

// ---------------------------------------------------------------------------
// 6. pack W (fp32 [128][200]) -> bf16 MFMA B-fragment order
//    layout: [kt][nt][lane][8j], one head per launch
//    B-frag for 16x16x32: lane holds B[k = quad*8 + j][n = lane&15]
// ---------------------------------------------------------------------------
__global__ void pack_w_kernel(const float* __restrict__ W, unsigned short* __restrict__ out) {
    int tid = blockIdx.x * blockDim.x + threadIdx.x;   // KT*NT*64 = 3328
    if (tid >= KT_TILES * NT_TILES * 64) return;
    int lane = tid & 63;
    int nt = (tid >> 6) % NT_TILES;
    int kt = tid / (64 * NT_TILES);
    int q = lane >> 4, r = lane & 15;
    int nn = nt * 16 + r;
    for (int j = 0; j < 8; j++) {
        int k = kt * 32 + q * 8 + j;
        float val = (nn < OUT_C) ? W[(size_t)k * OUT_C + nn] : 0.f;
        out[(size_t)tid * 8 + j] = (unsigned short)bf16_bits(val);
    }
}

// ---------------------------------------------------------------------------
// 7. fused 2-head MFMA GEMM: mu/ls[M,200] = agg[M,128] @ Wh + bh
//    block = 4 waves; wave w owns rows blockIdx.x*64 + w*16 .. +15
//    A frags held in registers (4 k-steps), B frags streamed from packed W.
// ---------------------------------------------------------------------------
__global__ __launch_bounds__(256) void gemm_mfma_kernel(
        const unsigned short* __restrict__ agg,   // [M][128] bf16
        const unsigned short* __restrict__ Wpk,   // [2][KT][NT][64][8] bf16
        const float* __restrict__ b1, const float* __restrict__ b2,
        float* __restrict__ mu, float* __restrict__ ls, int M) {
    int wave = threadIdx.x >> 6;
    int lane = threadIdx.x & 63;
    int row0 = blockIdx.x * 64 + wave * 16;
    int q = lane >> 4, r = lane & 15;

    // --- A fragments: A[m = lane&15][k = q*8 + j], kt-step = 32 ---
    int arow = row0 + r; if (arow > M - 1) arow = M - 1;
    const unsigned short* ap = agg + (size_t)arow * IN_C + q * 8;
    bf16x8 afrag[KT_TILES];
    #pragma unroll
    for (int kt = 0; kt < KT_TILES; kt++) {
        uint4 u = *(const uint4*)(ap + kt * 32);
        afrag[kt] = __builtin_bit_cast(bf16x8, u);
    }

    const size_t head_stride = (size_t)KT_TILES * NT_TILES * 64 * 8;
    const size_t kt_stride   = (size_t)NT_TILES * 64 * 8;

    f32x4 acc[2][NT_TILES];
    #pragma unroll
    for (int h = 0; h < 2; h++)
        #pragma unroll
        for (int nt = 0; nt < NT_TILES; nt++)
            acc[h][nt] = (f32x4){0.f, 0.f, 0.f, 0.f};

    #pragma unroll
    for (int nt = 0; nt < NT_TILES; nt++) {
        #pragma unroll
        for (int h = 0; h < 2; h++) {
            const unsigned short* wp = Wpk + h * head_stride + ((size_t)nt * 64 + lane) * 8;
            f32x4 c = acc[h][nt];
            #pragma unroll
            for (int kt = 0; kt < KT_TILES; kt++) {
                uint4 u = *(const uint4*)(wp + kt * kt_stride);
                bf16x8 bfrag = __builtin_bit_cast(bf16x8, u);
                c = __builtin_amdgcn_mfma_f32_16x16x32_bf16(afrag[kt], bfrag, c, 0, 0, 0);
            }
            acc[h][nt] = c;
        }
    }

    // --- epilogue: C/D layout col = lane&15, row = q*4 + reg ---
    #pragma unroll
    for (int nt = 0; nt < NT_TILES; nt++) {
        int col = nt * 16 + r;
        bool cok = col < OUT_C;
        float bv1 = cok ? b1[col] : 0.f;
        float bv2 = cok ? b2[col] : 0.f;
        #pragma unroll
        for (int reg = 0; reg < 4; reg++) {
            int gr = row0 + q * 4 + reg;
            if (cok && gr < M) {
                mu[(size_t)gr * OUT_C + col] = acc[0][nt][reg] + bv1;
                ls[(size_t)gr * OUT_C + col] = acc[1][nt][reg] + bv2;
            }
        }
    }
}

// ---------------------------------------------------------------------------
extern "C" void kernel_launch(void* const* d_in, const int* in_sizes, int n_in,
                              void* d_out, int out_size, void* d_ws, size_t ws_size,
                              hipStream_t stream) {
    const float* x  = (const float*)d_in[0];
    const int*   ei = (const int*)d_in[1];
    const float* W1 = (const float*)d_in[2];
    const float* b1 = (const float*)d_in[3];
    const float* W2 = (const float*)d_in[4];
    const float* b2 = (const float*)d_in[5];

    const int n = in_sizes[0] / IN_C;      // 100000
    const int E = in_sizes[1] / 2;         // 1600000
    const int* row = ei;                   // src
    const int* col = ei + E;               // dst

    float* mu = (float*)d_out;
    float* ls = (float*)d_out + (size_t)n * OUT_C;

    // workspace layout (byte offsets, 16B aligned)
    char* ws = (char*)d_ws;
    int*            deg     = (int*)           (ws + 0);
    float*          dinv    = (float*)         (ws + 524288);
    int*            offsets = (int*)           (ws + 1048576);
    int*            cursor  = (int*)           (ws + 1572864);
    int*            bsums   = (int*)           (ws + 2097152);
    int*            csr_src = (int*)           (ws + 2162688);          // E ints
    unsigned int*   xs2     = (unsigned int*)  (ws + 8562688);          // n*64 uints
    unsigned int*   agg2    = (unsigned int*)  (ws + 34162688);         // n*64 uints
    unsigned short* Wpk     = (unsigned short*)(ws + 59762688);         // 2*3328*8 bf16
    // total 59,869,184 B (< previous 59.96 MB footprint)

    const int nb_scan = (n + SCAN_CHUNK - 1) / SCAN_CHUNK;

    hipMemsetAsync(deg, 0, (size_t)n * sizeof(int), stream);

    count_deg_kernel<<<(E + 255) / 256, 256, 0, stream>>>(col, E, deg);
    dinv_kernel<<<(n + 255) / 256, 256, 0, stream>>>(deg, dinv, n);

    convert_xs_kernel<<<(n * 64 + 255) / 256, 256, 0, stream>>>(x, dinv, xs2, n);

    scan1_kernel<<<nb_scan, 256, 0, stream>>>(deg, n, bsums);
    scan2_kernel<<<1, 64, 0, stream>>>(bsums, nb_scan);
    scan3_kernel<<<nb_scan, 256, 0, stream>>>(deg, n, bsums, offsets, cursor);

    fill_kernel<<<(E + 255) / 256, 256, 0, stream>>>(row, col, E, cursor, csr_src);

    pack_w_kernel<<<(KT_TILES * NT_TILES * 64 + 255) / 256, 256, 0, stream>>>(W1, Wpk);
    pack_w_kernel<<<(KT_TILES * NT_TILES * 64 + 255) / 256, 256, 0, stream>>>(
        W2, Wpk + (size_t)KT_TILES * NT_TILES * 64 * 8);

    gather_kernel<<<(n + 3) / 4, 256, 0, stream>>>(xs2, dinv, offsets, deg, csr_src, agg2, n);

    gemm_mfma_kernel<<<(n + 63) / 64, 256, 0, stream>>>(
        (const unsigned short*)agg2, Wpk, b1, b2, mu, ls, n);
}

// Round 3
// 558.877 us; speedup vs baseline: 1.3765x; 1.1909x over previous
//
#include <hip/hip_runtime.h>

#define N_NODES 100000
#define IN_C    128
#define OUT_C   200
#define SCAN_CHUNK 1024
#define NT_TILES 13            // ceil(200/16)
#define KT_TILES 4             // 128/32

typedef __bf16 bf16_t;
typedef bf16_t bf16x8 __attribute__((ext_vector_type(8)));
typedef float  f32x4  __attribute__((ext_vector_type(4)));

// ---- bf16 bit helpers (RNE) -----------------------------------------------
__device__ __forceinline__ unsigned int bf16_bits(float f) {
    unsigned int u = __builtin_bit_cast(unsigned int, f);
    return (u + 0x7FFFu + ((u >> 16) & 1u)) >> 16;
}
__device__ __forceinline__ float bf16_lo(unsigned int p) {
    return __builtin_bit_cast(float, p << 16);
}
__device__ __forceinline__ float bf16_hi(unsigned int p) {
    return __builtin_bit_cast(float, p & 0xFFFF0000u);
}

// ---------------------------------------------------------------------------
// 1. degree count
// ---------------------------------------------------------------------------
__global__ void count_deg_kernel(const int* __restrict__ col, int E, int* __restrict__ deg) {
    int e = blockIdx.x * blockDim.x + threadIdx.x;
    if (e < E) atomicAdd(&deg[col[e]], 1);
}

__global__ void dinv_kernel(const int* __restrict__ deg, float* __restrict__ dinv, int n) {
    int v = blockIdx.x * blockDim.x + threadIdx.x;
    if (v < n) dinv[v] = rsqrtf((float)(deg[v] + 1));  // +1 self-loop
}

// ---------------------------------------------------------------------------
// 2. xs = dinv[v] * x[v]  ->  packed bf16x2
// ---------------------------------------------------------------------------
__global__ void convert_xs_kernel(const float* __restrict__ x, const float* __restrict__ dinv,
                                  unsigned int* __restrict__ xs2, int n) {
    int id = blockIdx.x * blockDim.x + threadIdx.x;   // n*64 total
    if (id >= n * 64) return;
    int v = id >> 6;
    float dv = dinv[v];
    float2 f = ((const float2*)x)[id];
    unsigned int lo = bf16_bits(f.x * dv);
    unsigned int hi = bf16_bits(f.y * dv);
    xs2[id] = lo | (hi << 16);
}

// ---------------------------------------------------------------------------
// 3. exclusive scan of deg -> CSR offsets
// ---------------------------------------------------------------------------
__global__ void scan1_kernel(const int* __restrict__ deg, int n, int* __restrict__ blockSums) {
    __shared__ int s[256];
    int base = blockIdx.x * SCAN_CHUNK;
    int sum = 0;
    for (int i = threadIdx.x; i < SCAN_CHUNK; i += 256) {
        int idx = base + i;
        sum += (idx < n) ? deg[idx] : 0;
    }
    s[threadIdx.x] = sum; __syncthreads();
    for (int off = 128; off > 0; off >>= 1) {
        if (threadIdx.x < off) s[threadIdx.x] += s[threadIdx.x + off];
        __syncthreads();
    }
    if (threadIdx.x == 0) blockSums[blockIdx.x] = s[0];
}

// parallel exclusive scan over nb (<=128) block sums — was a 40 µs serial loop
__global__ void scan2_kernel(int* __restrict__ blockSums, int nb) {
    __shared__ int s[128];
    int t = threadIdx.x;
    int v = (t < nb) ? blockSums[t] : 0;
    s[t] = v; __syncthreads();
    for (int off = 1; off < 128; off <<= 1) {
        int u = (t >= off) ? s[t - off] : 0;
        __syncthreads();
        s[t] += u;
        __syncthreads();
    }
    if (t < nb) blockSums[t] = s[t] - v;   // exclusive
}

__global__ void scan3_kernel(const int* __restrict__ deg, int n,
                             const int* __restrict__ blockSums,
                             int* __restrict__ offsets, int* __restrict__ cursor) {
    __shared__ int s[256];
    int base = blockIdx.x * SCAN_CHUNK;
    int vals[4];
    int tsum = 0;
    for (int j = 0; j < 4; j++) {
        int idx = base + threadIdx.x * 4 + j;
        vals[j] = (idx < n) ? deg[idx] : 0;
        tsum += vals[j];
    }
    s[threadIdx.x] = tsum; __syncthreads();
    for (int off = 1; off < 256; off <<= 1) {
        int t = (threadIdx.x >= (unsigned)off) ? s[threadIdx.x - off] : 0;
        __syncthreads();
        s[threadIdx.x] += t;
        __syncthreads();
    }
    int excl = s[threadIdx.x] - tsum + blockSums[blockIdx.x];
    for (int j = 0; j < 4; j++) {
        int idx = base + threadIdx.x * 4 + j;
        if (idx < n) { offsets[idx] = excl; cursor[idx] = excl; }
        excl += vals[j];
    }
}

// ---------------------------------------------------------------------------
// 4. CSR fill
// ---------------------------------------------------------------------------
__global__ void fill_kernel(const int* __restrict__ rowi, const int* __restrict__ coli, int E,
                            int* __restrict__ cursor, int* __restrict__ csr_src) {
    int e = blockIdx.x * blockDim.x + threadIdx.x;
    if (e < E) {
        int c = coli[e];
        int p = atomicAdd(&cursor[c], 1);
        csr_src[p] = rowi[e];
    }
}

// ---------------------------------------------------------------------------
// 5. gather: agg[v] = dv * ( xs[v] + sum_{u->v} xs[u] )
//    one wave per node; unrolled 8/4/1 so up to 8 row-loads are in flight
//    (R2 post-mortem: serial chain was latency-bound at 18% HBM, VALU 17%)
// ---------------------------------------------------------------------------
__global__ __launch_bounds__(256) void gather_kernel(
        const unsigned int* __restrict__ xs2, const float* __restrict__ dinv,
        const int* __restrict__ offsets, const int* __restrict__ deg,
        const int* __restrict__ csr_src, unsigned int* __restrict__ agg2, int n) {
    int wave = threadIdx.x >> 6;
    int lane = threadIdx.x & 63;
    int v = blockIdx.x * 4 + wave;
    if (v >= n) return;
    float dv = dinv[v];
    int start = offsets[v];
    int cnt = deg[v];
    unsigned int s = xs2[(size_t)v * 64 + lane];
    float ax = bf16_lo(s), ay = bf16_hi(s);

    const int* cp = csr_src + start;
    int i = 0;
    for (; i + 8 <= cnt; i += 8) {
        int u[8];
        #pragma unroll
        for (int j = 0; j < 8; j++) u[j] = cp[i + j];
        unsigned int t[8];
        #pragma unroll
        for (int j = 0; j < 8; j++) t[j] = xs2[(size_t)u[j] * 64 + lane];
        #pragma unroll
        for (int j = 0; j < 8; j++) { ax += bf16_lo(t[j]); ay += bf16_hi(t[j]); }
    }
    if (i + 4 <= cnt) {
        int u[4];
        #pragma unroll
        for (int j = 0; j < 4; j++) u[j] = cp[i + j];
        unsigned int t[4];
        #pragma unroll
        for (int j = 0; j < 4; j++) t[j] = xs2[(size_t)u[j] * 64 + lane];
        #pragma unroll
        for (int j = 0; j < 4; j++) { ax += bf16_lo(t[j]); ay += bf16_hi(t[j]); }
        i += 4;
    }
    for (; i < cnt; i++) {
        int u = cp[i];
        unsigned int t = xs2[(size_t)u * 64 + lane];
        ax += bf16_lo(t); ay += bf16_hi(t);
    }
    ax *= dv; ay *= dv;
    agg2[(size_t)v * 64 + lane] = bf16_bits(ax) | (bf16_bits(ay) << 16);
}

// ---------------------------------------------------------------------------
// 6. pack W1+W2 -> bf16 MFMA B-fragment order, nt-major for contiguous
//    per-nt LDS staging: layout [nt][h][kt][lane][8]
// ---------------------------------------------------------------------------
__global__ void pack_w_kernel(const float* __restrict__ W1, const float* __restrict__ W2,
                              unsigned short* __restrict__ out) {
    int tid = blockIdx.x * blockDim.x + threadIdx.x;   // 2*KT*NT*64 = 6656
    if (tid >= 2 * KT_TILES * NT_TILES * 64) return;
    int lane = tid & 63;
    int nt = (tid >> 6) % NT_TILES;
    int kt = (tid / (64 * NT_TILES)) % KT_TILES;
    int h  = tid / (64 * NT_TILES * KT_TILES);
    const float* W = h ? W2 : W1;
    int q = lane >> 4, r = lane & 15;
    int nn = nt * 16 + r;
    size_t dst = ((size_t)((nt * 2 + h) * KT_TILES + kt)) * 512 + (size_t)lane * 8;
    for (int j = 0; j < 8; j++) {
        int k = kt * 32 + q * 8 + j;
        float val = (nn < OUT_C) ? W[(size_t)k * OUT_C + nn] : 0.f;
        out[dst + j] = (unsigned short)bf16_bits(val);
    }
}

// ---------------------------------------------------------------------------
// 7. fused 2-head MFMA GEMM with per-nt LDS staging of B (double-buffered,
//    register prefetch, one barrier per nt)
// ---------------------------------------------------------------------------
__global__ __launch_bounds__(256) void gemm_mfma_kernel(
        const unsigned short* __restrict__ agg,   // [M][128] bf16
        const unsigned short* __restrict__ Wpk,   // [NT][2][KT][64][8] bf16
        const float* __restrict__ b1, const float* __restrict__ b2,
        float* __restrict__ mu, float* __restrict__ ls, int M) {
    __shared__ uint4 Bs[2][512];                  // 2 x 8KB nt-slices
    int tid  = threadIdx.x;
    int wave = tid >> 6;
    int lane = tid & 63;
    int row0 = blockIdx.x * 64 + wave * 16;
    int q = lane >> 4, r = lane & 15;

    // A fragments: A[m = lane&15][k = q*8 + j], one per kt
    int arow = row0 + r; if (arow > M - 1) arow = M - 1;
    const unsigned short* ap = agg + (size_t)arow * IN_C + q * 8;
    bf16x8 afrag[KT_TILES];
    #pragma unroll
    for (int kt = 0; kt < KT_TILES; kt++) {
        uint4 u = *(const uint4*)(ap + kt * 32);
        afrag[kt] = __builtin_bit_cast(bf16x8, u);
    }

    f32x4 acc[2][NT_TILES];
    #pragma unroll
    for (int h = 0; h < 2; h++)
        #pragma unroll
        for (int nt = 0; nt < NT_TILES; nt++)
            acc[h][nt] = (f32x4){0.f, 0.f, 0.f, 0.f};

    const uint4* wsrc = (const uint4*)Wpk;
    uint4 pre0 = wsrc[tid];
    uint4 pre1 = wsrc[tid + 256];

    for (int nt = 0; nt < NT_TILES; nt++) {
        int buf = nt & 1;
        Bs[buf][tid]       = pre0;
        Bs[buf][tid + 256] = pre1;
        __syncthreads();
        if (nt + 1 < NT_TILES) {
            pre0 = wsrc[(nt + 1) * 512 + tid];
            pre1 = wsrc[(nt + 1) * 512 + tid + 256];
        }
        #pragma unroll
        for (int h = 0; h < 2; h++) {
            f32x4 c = acc[h][nt];
            #pragma unroll
            for (int kt = 0; kt < KT_TILES; kt++) {
                uint4 u = Bs[buf][(h * KT_TILES + kt) * 64 + lane];
                bf16x8 bfrag = __builtin_bit_cast(bf16x8, u);
                c = __builtin_amdgcn_mfma_f32_16x16x32_bf16(afrag[kt], bfrag, c, 0, 0, 0);
            }
            acc[h][nt] = c;
        }
        // no second barrier needed: buffer written next at nt+2, by which time
        // all waves have passed the nt+1 barrier (i.e. finished reading it)
    }

    // epilogue: C/D layout col = lane&15, row = q*4 + reg
    #pragma unroll
    for (int nt = 0; nt < NT_TILES; nt++) {
        int col = nt * 16 + r;
        bool cok = col < OUT_C;
        float bv1 = cok ? b1[col] : 0.f;
        float bv2 = cok ? b2[col] : 0.f;
        #pragma unroll
        for (int reg = 0; reg < 4; reg++) {
            int gr = row0 + q * 4 + reg;
            if (cok && gr < M) {
                mu[(size_t)gr * OUT_C + col] = acc[0][nt][reg] + bv1;
                ls[(size_t)gr * OUT_C + col] = acc[1][nt][reg] + bv2;
            }
        }
    }
}

// ---------------------------------------------------------------------------
extern "C" void kernel_launch(void* const* d_in, const int* in_sizes, int n_in,
                              void* d_out, int out_size, void* d_ws, size_t ws_size,
                              hipStream_t stream) {
    const float* x  = (const float*)d_in[0];
    const int*   ei = (const int*)d_in[1];
    const float* W1 = (const float*)d_in[2];
    const float* b1 = (const float*)d_in[3];
    const float* W2 = (const float*)d_in[4];
    const float* b2 = (const float*)d_in[5];

    const int n = in_sizes[0] / IN_C;      // 100000
    const int E = in_sizes[1] / 2;         // 1600000
    const int* row = ei;                   // src
    const int* col = ei + E;               // dst

    float* mu = (float*)d_out;
    float* ls = (float*)d_out + (size_t)n * OUT_C;

    // workspace layout (byte offsets, 16B aligned)
    char* ws = (char*)d_ws;
    int*            deg     = (int*)           (ws + 0);
    float*          dinv    = (float*)         (ws + 524288);
    int*            offsets = (int*)           (ws + 1048576);
    int*            cursor  = (int*)           (ws + 1572864);
    int*            bsums   = (int*)           (ws + 2097152);
    int*            csr_src = (int*)           (ws + 2162688);          // E ints
    unsigned int*   xs2     = (unsigned int*)  (ws + 8562688);          // n*64 uints
    unsigned int*   agg2    = (unsigned int*)  (ws + 34162688);         // n*64 uints
    unsigned short* Wpk     = (unsigned short*)(ws + 59762688);         // 2*3328*8 bf16

    const int nb_scan = (n + SCAN_CHUNK - 1) / SCAN_CHUNK;

    hipMemsetAsync(deg, 0, (size_t)n * sizeof(int), stream);

    count_deg_kernel<<<(E + 255) / 256, 256, 0, stream>>>(col, E, deg);
    dinv_kernel<<<(n + 255) / 256, 256, 0, stream>>>(deg, dinv, n);

    convert_xs_kernel<<<(n * 64 + 255) / 256, 256, 0, stream>>>(x, dinv, xs2, n);

    scan1_kernel<<<nb_scan, 256, 0, stream>>>(deg, n, bsums);
    scan2_kernel<<<1, 128, 0, stream>>>(bsums, nb_scan);
    scan3_kernel<<<nb_scan, 256, 0, stream>>>(deg, n, bsums, offsets, cursor);

    fill_kernel<<<(E + 255) / 256, 256, 0, stream>>>(row, col, E, cursor, csr_src);

    pack_w_kernel<<<(2 * KT_TILES * NT_TILES * 64 + 255) / 256, 256, 0, stream>>>(W1, W2, Wpk);

    gather_kernel<<<(n + 3) / 4, 256, 0, stream>>>(xs2, dinv, offsets, deg, csr_src, agg2, n);

    gemm_mfma_kernel<<<(n + 63) / 64, 256, 0, stream>>>(
        (const unsigned short*)agg2, Wpk, b1, b2, mu, ls, n);
}